// Round 1
// baseline (65.436 us; speedup 1.0000x reference)
//
#include <hip/hip_runtime.h>

// ConcentrationLoss: pred,target [B=16,C=10,H=512,W=512] f32 -> scalar f32.
// Single fused streaming pass using moment expansion of the distance field.

#define BB 16
#define CC 10
#define HH 512
#define WW 512
#define HW (HH * WW)                 // 262144
#define SLICES (BB * CC)             // 160
#define CHUNKS 16                    // blocks per slice
#define V4_PER_CHUNK (HW / CHUNKS / 4)   // 4096 float4 per chunk
#define THREADS 256
#define V4_PER_THREAD (V4_PER_CHUNK / THREADS) // 16
#define NACC 8

__global__ __launch_bounds__(THREADS) void conc_pass1(
    const float* __restrict__ pred,
    const float* __restrict__ target,
    float* __restrict__ ws) {
  const int slice = blockIdx.x / CHUNKS;
  const int chunk = blockIdx.x % CHUNKS;
  const int tid = threadIdx.x;

  const float4* __restrict__ p4 =
      reinterpret_cast<const float4*>(pred + (size_t)slice * HW) + chunk * V4_PER_CHUNK;
  const float4* __restrict__ t4 =
      reinterpret_cast<const float4*>(target + (size_t)slice * HW) + chunk * V4_PER_CHUNK;

  float tm = 0.f, ty = 0.f, tx = 0.f;
  float s0 = 0.f, sy = 0.f, sx = 0.f, syy = 0.f, sxx = 0.f;

#pragma unroll
  for (int i = 0; i < V4_PER_THREAD; ++i) {
    const int v = i * THREADS + tid;           // float4 index within chunk
    const float4 t = t4[v];
    const float4 p = p4[v];
    const int e = (chunk * V4_PER_CHUNK + v) * 4;  // element index in slice
    const float y  = (float)(e >> 9);          // row (W=512)
    const float x0 = (float)(e & 511);         // col of .x lane (row-aligned: e%4==0)
    const float x1 = x0 + 1.f, x2 = x0 + 2.f, x3 = x0 + 3.f;

    // target moments
    const float tsum = (t.x + t.y) + (t.z + t.w);
    tm += tsum;
    ty += tsum * y;
    tx += t.x * x0 + t.y * x1 + t.z * x2 + t.w * x3;

    // sigmoid(pred) moments
    const float g0 = 1.f / (1.f + __expf(-p.x));
    const float g1 = 1.f / (1.f + __expf(-p.y));
    const float g2 = 1.f / (1.f + __expf(-p.z));
    const float g3 = 1.f / (1.f + __expf(-p.w));
    const float gs = (g0 + g1) + (g2 + g3);
    s0  += gs;
    sy  += gs * y;
    syy += gs * (y * y);
    const float gx = g0 * x0 + g1 * x1 + g2 * x2 + g3 * x3;
    sx  += gx;
    sxx += g0 * (x0 * x0) + g1 * (x1 * x1) + g2 * (x2 * x2) + g3 * (x3 * x3);
  }

  // block reduction: wave64 shuffle, then across the 4 waves via LDS
  float acc[NACC] = {tm, ty, tx, s0, sy, sx, syy, sxx};
#pragma unroll
  for (int k = 0; k < NACC; ++k) {
    float v = acc[k];
#pragma unroll
    for (int off = 32; off > 0; off >>= 1) v += __shfl_down(v, off, 64);
    acc[k] = v;
  }
  __shared__ float red[4][NACC];
  const int lane = tid & 63, wave = tid >> 6;
  if (lane == 0) {
#pragma unroll
    for (int k = 0; k < NACC; ++k) red[wave][k] = acc[k];
  }
  __syncthreads();
  if (tid == 0) {
    float* out = ws + (size_t)blockIdx.x * NACC;
#pragma unroll
    for (int k = 0; k < NACC; ++k)
      out[k] = red[0][k] + red[1][k] + red[2][k] + red[3][k];
  }
}

__global__ __launch_bounds__(THREADS) void conc_pass2(
    const float* __restrict__ ws, float* __restrict__ out) {
  const int tid = threadIdx.x;
  double lsum = 0.0;
  int nvalid = 0;

  for (int s = tid; s < SLICES; s += THREADS) {
    float a[NACC];
#pragma unroll
    for (int k = 0; k < NACC; ++k) a[k] = 0.f;
    for (int c = 0; c < CHUNKS; ++c) {
      const float* p = ws + (size_t)(s * CHUNKS + c) * NACC;
#pragma unroll
      for (int k = 0; k < NACC; ++k) a[k] += p[k];
    }
    const double tm = a[0], ty = a[1], tx = a[2];
    const double s0 = a[3], sy = a[4], sx = a[5], syy = a[6], sxx = a[7];
    const bool valid = tm > 0.0;
    const double mass = valid ? tm : 1.0;
    const double cy = ty / mass, cx = tx / mass;
    const double conc =
        syy + sxx - 2.0 * cy * sy - 2.0 * cx * sx + (cy * cy + cx * cx) * s0;
    if (valid) {
      lsum += conc / (double)HW;
      ++nvalid;
    }
  }

  __shared__ double sd[THREADS];
  __shared__ int si[THREADS];
  sd[tid] = lsum;
  si[tid] = nvalid;
  __syncthreads();
  for (int off = THREADS / 2; off > 0; off >>= 1) {
    if (tid < off) {
      sd[tid] += sd[tid + off];
      si[tid] += si[tid + off];
    }
    __syncthreads();
  }
  if (tid == 0) {
    const double loss = (si[0] > 0) ? (sd[0] / (double)si[0]) : 0.0;
    out[0] = (float)loss;  // CONCENTRATION_WEIGHT = 1.0
  }
}

extern "C" void kernel_launch(void* const* d_in, const int* in_sizes, int n_in,
                              void* d_out, int out_size, void* d_ws, size_t ws_size,
                              hipStream_t stream) {
  const float* pred = (const float*)d_in[0];
  const float* target = (const float*)d_in[1];
  float* ws = (float*)d_ws;   // needs SLICES*CHUNKS*NACC*4 = 80 KiB
  float* out = (float*)d_out;

  conc_pass1<<<SLICES * CHUNKS, THREADS, 0, stream>>>(pred, target, ws);
  conc_pass2<<<1, THREADS, 0, stream>>>(ws, out);
}